// Round 3
// baseline (149.823 us; speedup 1.0000x reference)
//
#include <hip/hip_runtime.h>
#include <float.h>

#define NA_TOTAL 8400
#define BSZ 32
#define NMAX 64
#define BG_IDX 80

// -------- IoU exactly mirroring the reference formula (no fp contraction) ----
__device__ __forceinline__ float iou_pair(float ax1, float ay1, float ax2, float ay2,
                                          float bx1, float by1, float bx2, float by2) {
#pragma clang fp contract(off)
  float ltx = fmaxf(ax1, bx1);
  float lty = fmaxf(ay1, by1);
  float rbx = fminf(ax2, bx2);
  float rby = fminf(ay2, by2);
  float w = fmaxf(rbx - ltx, 0.0f);
  float h = fmaxf(rby - lty, 0.0f);
  float inter = w * h;
  float a1 = (ax2 - ax1) * (ay2 - ay1);
  float a2 = (bx2 - bx1) * (by2 - by1);
  return inter / (a1 + a2 - inter + 1e-9f);
}

// -------- Stage 1: one thread per (b,g). Top-9 per level via 5x5 grid window.
// All per-thread state in REGISTERS with compile-time indexing (round-1 lesson:
// runtime-indexed LDS arrays at 1 wave/SIMD = ~120cy dependent latency each).
// Window proof: gt center within half a cell of nearest grid point -> 3x3
// window dists <= 2.13*s < 2.5*s <= any dist outside the 5x5 window. Strict
// margin, so the true top-9 under (dist, idx) lex order lives in the window.
__global__ __launch_bounds__(64) void stage1_kernel(
    const float* __restrict__ anchors,   // [8400,4]
    const float* __restrict__ gt_boxes,  // [32,64,4]
    const float* __restrict__ mask_gt,   // [32,64]
    unsigned long long* __restrict__ mpos) {  // [32][8400] bitmask over g
#pragma clang fp contract(off)
  const int tid = threadIdx.x;            // 0..63
  const int t = blockIdx.x * 64 + tid;    // (b,g) flat
  const int b = t >> 6;
  const int g = t & 63;

  if (mask_gt[t] <= 0.0f) return;

  const float4 gtb = ((const float4*)gt_boxes)[t];
  const float gx1 = gtb.x, gy1 = gtb.y, gx2 = gtb.z, gy2 = gtb.w;
  const float gcx = 0.5f * (gx1 + gx2);
  const float gcy = 0.5f * (gy1 + gy2);

  float io[3][25];      // registers (all indices compile-time)
  unsigned selm[3];
  int wx0s[3], wy0s[3];

#pragma unroll
  for (int lv = 0; lv < 3; ++lv) {
    const int strd = (lv == 0) ? 8 : (lv == 1) ? 16 : 32;
    const int n = (lv == 0) ? 80 : (lv == 1) ? 40 : 20;
    const int startA = (lv == 0) ? 0 : (lv == 1) ? 6400 : 8000;
    const float inv = 1.0f / (float)strd;

    int ix0 = (int)floorf(gcx * inv);
    int iy0 = (int)floorf(gcy * inv);
    ix0 = min(max(ix0, 0), n - 1);
    iy0 = min(max(iy0, 0), n - 1);
    int wx0 = min(max(ix0 - 2, 0), n - 5);
    int wy0 = min(max(iy0 - 2, 0), n - 5);
    wx0s[lv] = wx0;
    wy0s[lv] = wy0;

    float d[25];
#pragma unroll
    for (int i = 0; i < 25; ++i) {
      int a = startA + (wy0 + i / 5) * n + (wx0 + i % 5);
      float4 ab = ((const float4*)anchors)[a];
      float acx = 0.5f * (ab.x + ab.z);
      float acy = 0.5f * (ab.y + ab.w);
      float dx = gcx - acx;
      float dy = gcy - acy;
      d[i] = sqrtf(dx * dx + dy * dy);
    }

    // select top-9 under (dist, idx) lex order: rank-by-count, branchless
    unsigned m = 0;
#pragma unroll
    for (int i = 0; i < 25; ++i) {
      int cnt = 0;
#pragma unroll
      for (int j = 0; j < 25; ++j) {
        cnt += (int)((d[j] < d[i]) | ((d[j] == d[i]) & (j < i)));
      }
      m |= (unsigned)(cnt < 9) << i;
    }
    selm[lv] = m;

#pragma unroll
    for (int i = 0; i < 25; ++i) {
      int a = startA + (wy0 + i / 5) * n + (wx0 + i % 5);
      float4 ab = ((const float4*)anchors)[a];
      io[lv][i] = iou_pair(gx1, gy1, gx2, gy2, ab.x, ab.y, ab.z, ab.w);
    }
  }

  // thr = mean + std (ddof=1), double accumulation, two-pass.
  // Sum in slot order with +0.0 for unselected slots == compacted-order sum
  // bit-exactly (x + 0.0 preserves every partial; all io >= 0).
  double s = 0.0;
#pragma unroll
  for (int lv = 0; lv < 3; ++lv)
#pragma unroll
    for (int i = 0; i < 25; ++i)
      s += ((selm[lv] >> i) & 1u) ? (double)io[lv][i] : 0.0;
  double mean = s / 27.0;
  double s2 = 0.0;
#pragma unroll
  for (int lv = 0; lv < 3; ++lv)
#pragma unroll
    for (int i = 0; i < 25; ++i) {
      double dd = (double)io[lv][i] - mean;
      s2 += ((selm[lv] >> i) & 1u) ? dd * dd : 0.0;
    }
  float thr = (float)(mean + sqrt(s2 / 26.0));

#pragma unroll
  for (int lv = 0; lv < 3; ++lv) {
    const int n = (lv == 0) ? 80 : (lv == 1) ? 40 : 20;
    const int startA = (lv == 0) ? 0 : (lv == 1) ? 6400 : 8000;
#pragma unroll
    for (int i = 0; i < 25; ++i) {
      if (((selm[lv] >> i) & 1u) && io[lv][i] > thr) {
        int a = startA + (wy0s[lv] + i / 5) * n + (wx0s[lv] + i % 5);
        float4 ab = ((const float4*)anchors)[a];
        float acx = 0.5f * (ab.x + ab.z);
        float acy = 0.5f * (ab.y + ab.w);
        float d_in = fminf(fminf(acx - gx1, acy - gy1), fminf(gx2 - acx, gy2 - acy));
        if (d_in > 1e-9f) {
          atomicOr(&mpos[(size_t)b * NA_TOTAL + a], 1ull << g);
        }
      }
    }
  }
}

// -------- Stage 2: per (b,a) -> resolve multi-assignment, write all but scores
__global__ __launch_bounds__(256) void stage2_kernel(
    const float* __restrict__ anchors,   // [8400,4]
    const float* __restrict__ gt_boxes,  // [32,64,4]
    const int* __restrict__ labels,      // [32,64]
    const float* __restrict__ pred,      // [32,8400,4]
    const unsigned long long* __restrict__ mpos,
    float* __restrict__ out_lab,   // [32,8400]
    float* __restrict__ out_box,   // [32,8400,4]
    float* __restrict__ out_fgm,   // [32,8400]
    float* __restrict__ im_ws) {   // [32,8400] iou_max stash for stage 3
#pragma clang fp contract(off)
  const int b = blockIdx.y;
  const int a = blockIdx.x * 256 + threadIdx.x;

  __shared__ float4 gts[64];
  __shared__ int labs[64];
  if (threadIdx.x < 64) {
    gts[threadIdx.x] = ((const float4*)gt_boxes)[b * 64 + threadIdx.x];
    labs[threadIdx.x] = labels[b * 64 + threadIdx.x];
  }
  __syncthreads();
  if (a >= NA_TOTAL) return;

  const size_t idx = (size_t)b * NA_TOTAL + a;
  unsigned long long bits = mpos[idx];
  int fg = __popcll(bits);
  bool pos = fg > 0;
  int target = 0;
  if (fg == 1) {
    target = __builtin_ctzll(bits);
  } else if (fg > 1) {
    // anchor assigned to multiple gts -> argmax_g IoU(gt[g], anchor) (first max)
    float ax1 = anchors[a * 4 + 0], ay1 = anchors[a * 4 + 1];
    float ax2 = anchors[a * 4 + 2], ay2 = anchors[a * 4 + 3];
    float best = -1.0f;
    int bi = 0;
    for (int g2 = 0; g2 < 64; ++g2) {
      float4 gb = gts[g2];
      float v = iou_pair(gb.x, gb.y, gb.z, gb.w, ax1, ay1, ax2, ay2);
      if (v > best) { best = v; bi = g2; }
    }
    target = bi;
  }

  int lab = pos ? labs[target] : BG_IDX;
  out_lab[idx] = (float)lab;
  float4 tb = gts[target];  // background -> gt[0], matching reference
  ((float4*)out_box)[idx] = tb;
  out_fgm[idx] = pos ? 1.0f : 0.0f;
  float im = 0.0f;
  if (pos) {
    float4 pb = ((const float4*)pred)[idx];
    im = iou_pair(tb.x, tb.y, tb.z, tb.w, pb.x, pb.y, pb.z, pb.w);
  }
  im_ws[idx] = im;
}

// -------- Stage 3: fully-coalesced one-shot score write (replaces 86MB memset)
__global__ __launch_bounds__(256) void stage3_kernel(
    const float* __restrict__ out_lab,  // [32*8400] (written by stage 2)
    const float* __restrict__ im_ws,    // [32*8400]
    float4* __restrict__ out_sco4) {    // [32*8400*20] float4 view of scores
  const int u = blockIdx.x * 256 + threadIdx.x;  // float4 index
  const int total = BSZ * NA_TOTAL * 20;
  if (u >= total) return;
  const int anch = u / 20;
  const int q = u - anch * 20;  // which float4 of the 80-score row
  const int lab = (int)out_lab[anch];
  const float im = im_ws[anch];
  const int c0 = q * 4;
  float4 v;
  v.x = (lab == c0 + 0) ? im : 0.0f;
  v.y = (lab == c0 + 1) ? im : 0.0f;
  v.z = (lab == c0 + 2) ? im : 0.0f;
  v.w = (lab == c0 + 3) ? im : 0.0f;
  out_sco4[u] = v;
}

extern "C" void kernel_launch(void* const* d_in, const int* in_sizes, int n_in,
                              void* d_out, int out_size, void* d_ws, size_t ws_size,
                              hipStream_t stream) {
  const float* anchors = (const float*)d_in[0];
  // d_in[1] = num_anchors_list (compile-time constants here)
  const int* labels = (const int*)d_in[2];
  const float* gt_boxes = (const float*)d_in[3];
  const float* mask_gt = (const float*)d_in[4];
  const float* pred = (const float*)d_in[5];

  float* out = (float*)d_out;
  float* out_lab = out;                                    // 32*8400
  float* out_box = out + (size_t)BSZ * NA_TOTAL;           // 32*8400*4
  float* out_sco = out + (size_t)BSZ * NA_TOTAL * 5;       // 32*8400*80
  float* out_fgm = out + (size_t)BSZ * NA_TOTAL * 85;      // 32*8400

  unsigned long long* mpos = (unsigned long long*)d_ws;    // 2.15 MB
  float* im_ws = (float*)(mpos + (size_t)BSZ * NA_TOTAL);  // +1.07 MB

  hipMemsetAsync(mpos, 0, (size_t)BSZ * NA_TOTAL * sizeof(unsigned long long), stream);

  stage1_kernel<<<(BSZ * NMAX) / 64, 64, 0, stream>>>(anchors, gt_boxes, mask_gt, mpos);

  dim3 g2((NA_TOTAL + 255) / 256, BSZ);
  stage2_kernel<<<g2, 256, 0, stream>>>(anchors, gt_boxes, labels, pred, mpos,
                                        out_lab, out_box, out_fgm, im_ws);

  const int total4 = BSZ * NA_TOTAL * 20;
  stage3_kernel<<<(total4 + 255) / 256, 256, 0, stream>>>(out_lab, im_ws,
                                                          (float4*)out_sco);
}

// Round 4
// 52.409 us; speedup vs baseline: 2.8587x; 2.8587x over previous
//
#include <hip/hip_runtime.h>
#include <float.h>

#define NA_TOTAL 8400
#define BSZ 32
#define NMAX 64
#define BG_IDX 80

// -------- IoU exactly mirroring the reference formula (no fp contraction) ----
__device__ __forceinline__ float iou_pair(float ax1, float ay1, float ax2, float ay2,
                                          float bx1, float by1, float bx2, float by2) {
#pragma clang fp contract(off)
  float ltx = fmaxf(ax1, bx1);
  float lty = fmaxf(ay1, by1);
  float rbx = fminf(ax2, bx2);
  float rby = fminf(ay2, by2);
  float w = fmaxf(rbx - ltx, 0.0f);
  float h = fmaxf(rby - lty, 0.0f);
  float inter = w * h;
  float a1 = (ax2 - ax1) * (ay2 - ay1);
  float a2 = (bx2 - bx1) * (by2 - by1);
  return inter / (a1 + a2 - inter + 1e-9f);
}

// -------- Stage 1: ONE WAVE per (b,g). Lanes 0..24 own the 5x5 window slots.
// Round-3 lesson: one-thread-per-gt = 32 waves total -> nothing hides latency,
// and full unrolling made ~100KB of straight-line code (I-cache-miss-bound,
// FETCH_SIZE grew by exactly the code size). Here: 2048 waves (8/CU), rolled
// shuffle loops (tiny code), all hot state in registers.
// Window proof: gt center within half a cell of nearest grid point -> 3x3
// window dists <= 2.13*s < 2.5*s <= any dist outside the 5x5 window. Strict
// margin, so the true top-9 under (dist, idx) lex order lives in the window.
__global__ __launch_bounds__(256) void stage1_kernel(
    const float* __restrict__ anchors,   // [8400,4]
    const float* __restrict__ gt_boxes,  // [32,64,4]
    const float* __restrict__ mask_gt,   // [32,64]
    unsigned long long* __restrict__ mpos) {  // [32][8400] bitmask over g
#pragma clang fp contract(off)
  const int lane = threadIdx.x & 63;
  const int wid = threadIdx.x >> 6;            // 4 waves per block
  const int t = blockIdx.x * 4 + wid;          // (b,g) flat, wave-uniform
  const int b = t >> 6;
  const int g = t & 63;

  if (mask_gt[t] <= 0.0f) return;  // wave-uniform branch

  const float4 gtb = ((const float4*)gt_boxes)[t];
  const float gx1 = gtb.x, gy1 = gtb.y, gx2 = gtb.z, gy2 = gtb.w;
  const float gcx = 0.5f * (gx1 + gx2);
  const float gcy = 0.5f * (gy1 + gy2);

  float io_arr[3];                  // this lane's candidate IoU per level
  int aidx[3];                      // this lane's anchor index per level
  bool sel_arr[3];                  // selected in top-9?
  unsigned long long bal[3];        // ballot of selected lanes per level

#pragma unroll
  for (int lv = 0; lv < 3; ++lv) {
    const int strd = (lv == 0) ? 8 : (lv == 1) ? 16 : 32;
    const int n = (lv == 0) ? 80 : (lv == 1) ? 40 : 20;
    const int startA = (lv == 0) ? 0 : (lv == 1) ? 6400 : 8000;
    const float inv = 1.0f / (float)strd;

    int ix0 = (int)floorf(gcx * inv);
    int iy0 = (int)floorf(gcy * inv);
    ix0 = min(max(ix0, 0), n - 1);
    iy0 = min(max(iy0, 0), n - 1);
    int wx0 = min(max(ix0 - 2, 0), n - 5);
    int wy0 = min(max(iy0 - 2, 0), n - 5);

    // lane i (i<25) owns window slot i (slot order = increasing anchor index)
    int a = startA + (wy0 + lane / 5) * n + (wx0 + lane % 5);
    aidx[lv] = a;
    float d = FLT_MAX;
    float iov = 0.0f;
    if (lane < 25) {
      float4 ab = ((const float4*)anchors)[a];
      float acx = 0.5f * (ab.x + ab.z);
      float acy = 0.5f * (ab.y + ab.w);
      float dx = gcx - acx;
      float dy = gcy - acy;
      d = sqrtf(dx * dx + dy * dy);
      iov = iou_pair(gx1, gy1, gx2, gy2, ab.x, ab.y, ab.z, ab.w);
    }
    io_arr[lv] = iov;

    // rank via all-to-all compare over lanes 0..24 ((dist, idx) lex order)
    int cnt = 0;
    for (int j = 0; j < 25; ++j) {
      float dj = __shfl(d, j);
      cnt += (int)((dj < d) | ((dj == d) & (j < lane)));
    }
    bool sel = (lane < 25) && (cnt < 9);
    sel_arr[lv] = sel;
    bal[lv] = __ballot(sel);
  }

  // thr = mean + std (ddof=1), double accumulation, two-pass, slot order with
  // +0.0 for unselected slots — bit-identical to the passing round-2/3 math.
  // Computed redundantly by all 64 lanes (uniform shuffles).
  double s = 0.0;
#pragma unroll
  for (int lv = 0; lv < 3; ++lv) {
    for (int j = 0; j < 25; ++j) {
      float v = __shfl(io_arr[lv], j);
      s += ((bal[lv] >> j) & 1ull) ? (double)v : 0.0;
    }
  }
  double mean = s / 27.0;
  double s2 = 0.0;
#pragma unroll
  for (int lv = 0; lv < 3; ++lv) {
    for (int j = 0; j < 25; ++j) {
      float v = __shfl(io_arr[lv], j);
      double dd = (double)v - mean;
      s2 += ((bal[lv] >> j) & 1ull) ? dd * dd : 0.0;
    }
  }
  float thr = (float)(mean + sqrt(s2 / 26.0));

  // emit: selected & iou>thr & center strictly inside gt
#pragma unroll
  for (int lv = 0; lv < 3; ++lv) {
    if (sel_arr[lv] && io_arr[lv] > thr) {
      int a = aidx[lv];
      float4 ab = ((const float4*)anchors)[a];
      float acx = 0.5f * (ab.x + ab.z);
      float acy = 0.5f * (ab.y + ab.w);
      float d_in = fminf(fminf(acx - gx1, acy - gy1), fminf(gx2 - acx, gy2 - acy));
      if (d_in > 1e-9f) {
        atomicOr(&mpos[(size_t)b * NA_TOTAL + a], 1ull << g);
      }
    }
  }
}

// -------- Stage 2: per (b,a) -> resolve multi-assignment, write all but scores
__global__ __launch_bounds__(256) void stage2_kernel(
    const float* __restrict__ anchors,   // [8400,4]
    const float* __restrict__ gt_boxes,  // [32,64,4]
    const int* __restrict__ labels,      // [32,64]
    const float* __restrict__ pred,      // [32,8400,4]
    const unsigned long long* __restrict__ mpos,
    float* __restrict__ out_lab,   // [32,8400]
    float* __restrict__ out_box,   // [32,8400,4]
    float* __restrict__ out_fgm,   // [32,8400]
    float* __restrict__ im_ws) {   // [32,8400] iou_max stash for stage 3
#pragma clang fp contract(off)
  const int b = blockIdx.y;
  const int a = blockIdx.x * 256 + threadIdx.x;

  __shared__ float4 gts[64];
  __shared__ int labs[64];
  if (threadIdx.x < 64) {
    gts[threadIdx.x] = ((const float4*)gt_boxes)[b * 64 + threadIdx.x];
    labs[threadIdx.x] = labels[b * 64 + threadIdx.x];
  }
  __syncthreads();
  if (a >= NA_TOTAL) return;

  const size_t idx = (size_t)b * NA_TOTAL + a;
  unsigned long long bits = mpos[idx];
  int fg = __popcll(bits);
  bool pos = fg > 0;
  int target = 0;
  if (fg == 1) {
    target = __builtin_ctzll(bits);
  } else if (fg > 1) {
    // anchor assigned to multiple gts -> argmax_g IoU(gt[g], anchor) (first max)
    float ax1 = anchors[a * 4 + 0], ay1 = anchors[a * 4 + 1];
    float ax2 = anchors[a * 4 + 2], ay2 = anchors[a * 4 + 3];
    float best = -1.0f;
    int bi = 0;
    for (int g2 = 0; g2 < 64; ++g2) {
      float4 gb = gts[g2];
      float v = iou_pair(gb.x, gb.y, gb.z, gb.w, ax1, ay1, ax2, ay2);
      if (v > best) { best = v; bi = g2; }
    }
    target = bi;
  }

  int lab = pos ? labs[target] : BG_IDX;
  out_lab[idx] = (float)lab;
  float4 tb = gts[target];  // background -> gt[0], matching reference
  ((float4*)out_box)[idx] = tb;
  out_fgm[idx] = pos ? 1.0f : 0.0f;
  float im = 0.0f;
  if (pos) {
    float4 pb = ((const float4*)pred)[idx];
    im = iou_pair(tb.x, tb.y, tb.z, tb.w, pb.x, pb.y, pb.z, pb.w);
  }
  im_ws[idx] = im;
}

// -------- Stage 3: fully-coalesced one-shot score write (replaces 86MB memset)
__global__ __launch_bounds__(256) void stage3_kernel(
    const float* __restrict__ out_lab,  // [32*8400] (written by stage 2)
    const float* __restrict__ im_ws,    // [32*8400]
    float4* __restrict__ out_sco4) {    // [32*8400*20] float4 view of scores
  const int u = blockIdx.x * 256 + threadIdx.x;  // float4 index
  const int total = BSZ * NA_TOTAL * 20;
  if (u >= total) return;
  const int anch = u / 20;
  const int q = u - anch * 20;  // which float4 of the 80-score row
  const int lab = (int)out_lab[anch];
  const float im = im_ws[anch];
  const int c0 = q * 4;
  float4 v;
  v.x = (lab == c0 + 0) ? im : 0.0f;
  v.y = (lab == c0 + 1) ? im : 0.0f;
  v.z = (lab == c0 + 2) ? im : 0.0f;
  v.w = (lab == c0 + 3) ? im : 0.0f;
  out_sco4[u] = v;
}

extern "C" void kernel_launch(void* const* d_in, const int* in_sizes, int n_in,
                              void* d_out, int out_size, void* d_ws, size_t ws_size,
                              hipStream_t stream) {
  const float* anchors = (const float*)d_in[0];
  // d_in[1] = num_anchors_list (compile-time constants here)
  const int* labels = (const int*)d_in[2];
  const float* gt_boxes = (const float*)d_in[3];
  const float* mask_gt = (const float*)d_in[4];
  const float* pred = (const float*)d_in[5];

  float* out = (float*)d_out;
  float* out_lab = out;                                    // 32*8400
  float* out_box = out + (size_t)BSZ * NA_TOTAL;           // 32*8400*4
  float* out_sco = out + (size_t)BSZ * NA_TOTAL * 5;       // 32*8400*80
  float* out_fgm = out + (size_t)BSZ * NA_TOTAL * 85;      // 32*8400

  unsigned long long* mpos = (unsigned long long*)d_ws;    // 2.15 MB
  float* im_ws = (float*)(mpos + (size_t)BSZ * NA_TOTAL);  // +1.07 MB

  hipMemsetAsync(mpos, 0, (size_t)BSZ * NA_TOTAL * sizeof(unsigned long long), stream);

  // one wave per (b,g): 2048 waves, 4 waves (256 thr) per block
  stage1_kernel<<<(BSZ * NMAX) / 4, 256, 0, stream>>>(anchors, gt_boxes, mask_gt, mpos);

  dim3 g2((NA_TOTAL + 255) / 256, BSZ);
  stage2_kernel<<<g2, 256, 0, stream>>>(anchors, gt_boxes, labels, pred, mpos,
                                        out_lab, out_box, out_fgm, im_ws);

  const int total4 = BSZ * NA_TOTAL * 20;
  stage3_kernel<<<(total4 + 255) / 256, 256, 0, stream>>>(out_lab, im_ws,
                                                          (float4*)out_sco);
}

// Round 5
// 33.881 us; speedup vs baseline: 4.4221x; 1.5469x over previous
//
#include <hip/hip_runtime.h>
#include <float.h>

#define NA_TOTAL 8400
#define BSZ 32
#define NMAX 64
#define BG_IDX 80

// -------- IoU exactly mirroring the reference formula (no fp contraction) ----
__device__ __forceinline__ float iou_pair(float ax1, float ay1, float ax2, float ay2,
                                          float bx1, float by1, float bx2, float by2) {
#pragma clang fp contract(off)
  float ltx = fmaxf(ax1, bx1);
  float lty = fmaxf(ay1, by1);
  float rbx = fminf(ax2, bx2);
  float rby = fminf(ay2, by2);
  float w = fmaxf(rbx - ltx, 0.0f);
  float h = fmaxf(rby - lty, 0.0f);
  float inter = w * h;
  float a1 = (ax2 - ax1) * (ay2 - ay1);
  float a2 = (bx2 - bx1) * (by2 - by1);
  return inter / (a1 + a2 - inter + 1e-9f);
}

// -------- Stage 1: ONE WAVE per (b,g). Lanes 0..24 own the 5x5 window slots.
// Output: pos_list[b][g][27] = anchor index if that candidate is positive
// (top-9 by (dist,idx), iou>thr, center strictly inside gt) else -1.
// EVERY slot is written every call -> no pre-zeroing, no atomics, deterministic.
// Window proof: gt center within half a cell of nearest grid point -> 3x3
// window dists <= 2.13*s < 2.5*s <= any dist outside the 5x5 window. Strict
// margin, so the true top-9 under (dist, idx) lex order lives in the window.
__global__ __launch_bounds__(256) void stage1_kernel(
    const float* __restrict__ anchors,   // [8400,4]
    const float* __restrict__ gt_boxes,  // [32,64,4]
    const float* __restrict__ mask_gt,   // [32,64]
    int* __restrict__ pos_list) {        // [32*64*27]
#pragma clang fp contract(off)
  const int lane = threadIdx.x & 63;
  const int wid = threadIdx.x >> 6;            // 4 waves per block
  const int t = blockIdx.x * 4 + wid;          // (b,g) flat, wave-uniform

  if (mask_gt[t] <= 0.0f) {  // wave-uniform branch
    if (lane < 27) pos_list[t * 27 + lane] = -1;
    return;
  }

  const float4 gtb = ((const float4*)gt_boxes)[t];
  const float gx1 = gtb.x, gy1 = gtb.y, gx2 = gtb.z, gy2 = gtb.w;
  const float gcx = 0.5f * (gx1 + gx2);
  const float gcy = 0.5f * (gy1 + gy2);

  float io_arr[3];                  // this lane's candidate IoU per level
  int aidx[3];                      // this lane's anchor index per level
  bool sel_arr[3];                  // selected in top-9?
  unsigned long long bal[3];        // ballot of selected lanes per level

#pragma unroll
  for (int lv = 0; lv < 3; ++lv) {
    const int strd = (lv == 0) ? 8 : (lv == 1) ? 16 : 32;
    const int n = (lv == 0) ? 80 : (lv == 1) ? 40 : 20;
    const int startA = (lv == 0) ? 0 : (lv == 1) ? 6400 : 8000;
    const float inv = 1.0f / (float)strd;

    int ix0 = (int)floorf(gcx * inv);
    int iy0 = (int)floorf(gcy * inv);
    ix0 = min(max(ix0, 0), n - 1);
    iy0 = min(max(iy0, 0), n - 1);
    int wx0 = min(max(ix0 - 2, 0), n - 5);
    int wy0 = min(max(iy0 - 2, 0), n - 5);

    // lane i (i<25) owns window slot i (slot order = increasing anchor index)
    int a = startA + (wy0 + lane / 5) * n + (wx0 + lane % 5);
    aidx[lv] = a;
    float d = FLT_MAX;
    float iov = 0.0f;
    if (lane < 25) {
      float4 ab = ((const float4*)anchors)[a];
      float acx = 0.5f * (ab.x + ab.z);
      float acy = 0.5f * (ab.y + ab.w);
      float dx = gcx - acx;
      float dy = gcy - acy;
      d = sqrtf(dx * dx + dy * dy);
      iov = iou_pair(gx1, gy1, gx2, gy2, ab.x, ab.y, ab.z, ab.w);
    }
    io_arr[lv] = iov;

    // rank via all-to-all compare over lanes 0..24 ((dist, idx) lex order)
    int cnt = 0;
    for (int j = 0; j < 25; ++j) {
      float dj = __shfl(d, j);
      cnt += (int)((dj < d) | ((dj == d) & (j < lane)));
    }
    bool sel = (lane < 25) && (cnt < 9);
    sel_arr[lv] = sel;
    bal[lv] = __ballot(sel);
  }

  // thr = mean + std (ddof=1), double accumulation, two-pass, slot order with
  // +0.0 for unselected slots — bit-identical to the passing round-2/3/4 math.
  double s = 0.0;
#pragma unroll
  for (int lv = 0; lv < 3; ++lv) {
    for (int j = 0; j < 25; ++j) {
      float v = __shfl(io_arr[lv], j);
      s += ((bal[lv] >> j) & 1ull) ? (double)v : 0.0;
    }
  }
  double mean = s / 27.0;
  double s2 = 0.0;
#pragma unroll
  for (int lv = 0; lv < 3; ++lv) {
    for (int j = 0; j < 25; ++j) {
      float v = __shfl(io_arr[lv], j);
      double dd = (double)v - mean;
      s2 += ((bal[lv] >> j) & 1ull) ? dd * dd : 0.0;
    }
  }
  float thr = (float)(mean + sqrt(s2 / 26.0));

  // emit: each selected lane writes its entry (exactly 9 per level -> 27 total)
#pragma unroll
  for (int lv = 0; lv < 3; ++lv) {
    if (sel_arr[lv]) {
      int rank = (int)__popcll(bal[lv] & ((1ull << lane) - 1ull));
      int val = -1;
      if (io_arr[lv] > thr) {
        int a = aidx[lv];
        float4 ab = ((const float4*)anchors)[a];
        float acx = 0.5f * (ab.x + ab.z);
        float acy = 0.5f * (ab.y + ab.w);
        float d_in = fminf(fminf(acx - gx1, acy - gy1), fminf(gx2 - acx, gy2 - acy));
        if (d_in > 1e-9f) val = a;
      }
      pos_list[t * 27 + lv * 9 + rank] = val;
    }
  }
}

// -------- Stage 2 (fused): per (b, 256-anchor tile). Scatter pos_list into a
// per-anchor 64-bit gt mask in LDS, resolve assignment, write ALL outputs
// including the coalesced 80-wide score rows (old stage 3).
__global__ __launch_bounds__(256) void stage2_kernel(
    const float* __restrict__ anchors,   // [8400,4]
    const float* __restrict__ gt_boxes,  // [32,64,4]
    const int* __restrict__ labels,      // [32,64]
    const float* __restrict__ pred,      // [32,8400,4]
    const int* __restrict__ pos_list,    // [32*64*27]
    float* __restrict__ out_lab,   // [32,8400]
    float* __restrict__ out_box,   // [32,8400,4]
    float4* __restrict__ out_sco4, // [32*8400*20] float4 view of scores
    float* __restrict__ out_fgm) { // [32,8400]
#pragma clang fp contract(off)
  const int b = blockIdx.y;
  const int A0 = blockIdx.x * 256;
  const int tid = threadIdx.x;
  const int a = A0 + tid;

  __shared__ float4 gts[64];
  __shared__ int labs[64];
  __shared__ unsigned mLo[256];
  __shared__ unsigned mHi[256];
  __shared__ int plist[64 * 27];
  __shared__ int lab_s[256];
  __shared__ float im_s[256];

  if (tid < 64) {
    gts[tid] = ((const float4*)gt_boxes)[b * 64 + tid];
    labs[tid] = labels[b * 64 + tid];
  }
  mLo[tid] = 0u;
  mHi[tid] = 0u;
  for (int i = tid; i < 64 * 27; i += 256) plist[i] = pos_list[b * 64 * 27 + i];
  __syncthreads();

  // scatter: entry i belongs to gt g=i/27; set bit g on its anchor (if in tile)
  for (int i = tid; i < 64 * 27; i += 256) {
    int av = plist[i];
    if (av >= A0 && av < A0 + 256) {
      int g = i / 27;
      int la = av - A0;
      if (g < 32) atomicOr(&mLo[la], 1u << g);
      else        atomicOr(&mHi[la], 1u << (g - 32));
    }
  }
  __syncthreads();

  const bool valid = a < NA_TOTAL;
  int lab = BG_IDX;
  float im = 0.0f;
  if (valid) {
    unsigned long long bits =
        (unsigned long long)mLo[tid] | ((unsigned long long)mHi[tid] << 32);
    int fg = __popcll(bits);
    bool pos = fg > 0;
    int target = 0;
    if (fg == 1) {
      target = __builtin_ctzll(bits);
    } else if (fg > 1) {
      // multi-assignment -> argmax_g IoU(gt[g], anchor), first-max tie-break
      float4 ab = ((const float4*)anchors)[a];
      float best = -1.0f;
      int bi = 0;
      for (int g2 = 0; g2 < 64; ++g2) {
        float4 gb = gts[g2];
        float v = iou_pair(gb.x, gb.y, gb.z, gb.w, ab.x, ab.y, ab.z, ab.w);
        if (v > best) { best = v; bi = g2; }
      }
      target = bi;
    }
    lab = pos ? labs[target] : BG_IDX;
    const size_t idx = (size_t)b * NA_TOTAL + a;
    out_lab[idx] = (float)lab;
    float4 tb = gts[target];  // background -> gt[0], matching reference
    ((float4*)out_box)[idx] = tb;
    out_fgm[idx] = pos ? 1.0f : 0.0f;
    if (pos) {
      float4 pb = ((const float4*)pred)[idx];
      im = iou_pair(tb.x, tb.y, tb.z, tb.w, pb.x, pb.y, pb.z, pb.w);
    }
  }
  lab_s[tid] = lab;
  im_s[tid] = im;
  __syncthreads();

  // coalesced score write: float4 index k covers (local anchor k/20, quad k%20)
  const int ntile = min(NA_TOTAL - A0, 256);
  const int nval = ntile * 20;
  const size_t base = (size_t)b * NA_TOTAL * 20 + (size_t)A0 * 20;
  for (int k = tid; k < nval; k += 256) {
    int la = k / 20;
    int q = k - la * 20;
    int lb = lab_s[la];
    float v_im = im_s[la];
    int c0 = q * 4;
    float4 v;
    v.x = (lb == c0 + 0) ? v_im : 0.0f;
    v.y = (lb == c0 + 1) ? v_im : 0.0f;
    v.z = (lb == c0 + 2) ? v_im : 0.0f;
    v.w = (lb == c0 + 3) ? v_im : 0.0f;
    out_sco4[base + k] = v;
  }
}

extern "C" void kernel_launch(void* const* d_in, const int* in_sizes, int n_in,
                              void* d_out, int out_size, void* d_ws, size_t ws_size,
                              hipStream_t stream) {
  const float* anchors = (const float*)d_in[0];
  // d_in[1] = num_anchors_list (compile-time constants here)
  const int* labels = (const int*)d_in[2];
  const float* gt_boxes = (const float*)d_in[3];
  const float* mask_gt = (const float*)d_in[4];
  const float* pred = (const float*)d_in[5];

  float* out = (float*)d_out;
  float* out_lab = out;                                    // 32*8400
  float* out_box = out + (size_t)BSZ * NA_TOTAL;           // 32*8400*4
  float* out_sco = out + (size_t)BSZ * NA_TOTAL * 5;       // 32*8400*80
  float* out_fgm = out + (size_t)BSZ * NA_TOTAL * 85;      // 32*8400

  int* pos_list = (int*)d_ws;  // 32*64*27 ints = 221 KB; fully overwritten each call

  // one wave per (b,g): 2048 waves, 4 waves (256 thr) per block
  stage1_kernel<<<(BSZ * NMAX) / 4, 256, 0, stream>>>(anchors, gt_boxes, mask_gt,
                                                      pos_list);

  dim3 g2((NA_TOTAL + 255) / 256, BSZ);
  stage2_kernel<<<g2, 256, 0, stream>>>(anchors, gt_boxes, labels, pred, pos_list,
                                        out_lab, out_box, (float4*)out_sco, out_fgm);
}